// Round 14
// baseline (229.452 us; speedup 1.0000x reference)
//
#include <hip/hip_runtime.h>
#include <hip/hip_bf16.h>

typedef __attribute__((ext_vector_type(8))) short bf16x8;
typedef __attribute__((ext_vector_type(4))) float f32x4;

#define NB 8
#define NN 2048
#define DM 512
#define DF 1024

__device__ __forceinline__ ushort f2b(float f) {
  union { __hip_bfloat16 h; ushort u; } c;
  c.h = __float2bfloat16(f);
  return c.u;
}
__device__ __forceinline__ float b2f(ushort u) {
  union { ushort u; __hip_bfloat16 h; } c;
  c.u = u;
  return __bfloat162float(c.h);
}

typedef __attribute__((address_space(1))) const void gvoid_t;
typedef __attribute__((address_space(3))) void svoid_t;
__device__ __forceinline__ void gload16(const void* g, void* s) {
  __builtin_amdgcn_global_load_lds((gvoid_t*)g, (svoid_t*)s, 16, 0, 0);
}

// ---------------- 128x128 NT GEMM core, double-buffered (gemm1/2, pv) ------
__device__ __forceinline__ void gemm_core_128(
    const ushort* __restrict__ A, const ushort* __restrict__ B,
    int K, int brow, int bcol, f32x4 (&acc)[4][4], ushort* smem)
{
  const int tid = threadIdx.x;
  const int w = tid >> 6, l = tid & 63;
  const int sr = (w << 3) + (l >> 3);
  const int sc = (((l & 7) ^ (l >> 3)) << 3);
  const int fr = l & 15;
  const int arow = ((w >> 1) << 6) + fr;
  const int brw  = ((w & 1) << 6) + fr;
  char* base = (char*)smem;
  char* A0 = base;          char* B0 = base + 16384;
  char* A1 = base + 32768;  char* B1 = base + 49152;

#pragma unroll
  for (int m = 0; m < 4; m++)
#pragma unroll
    for (int n = 0; n < 4; n++)
      acc[m][n] = (f32x4){0.f, 0.f, 0.f, 0.f};

  const ushort* Ap = A + (long)(brow + sr) * K + sc;
  const ushort* Bp = B + (long)(bcol + sr) * K + sc;
  const int nkt = K >> 6;

  auto stage = [&](char* Ad, char* Bd, int kt) {
#pragma unroll
    for (int i = 0; i < 4; i++) {
      gload16(Ap + (long)i * 32 * K + kt * 64, Ad + i * 4096 + (w << 10));
      gload16(Bp + (long)i * 32 * K + kt * 64, Bd + i * 4096 + (w << 10));
    }
  };
  auto compute = [&](const char* As_, const char* Bs_) {
#pragma unroll
    for (int kk = 0; kk < 2; kk++) {
      const int cx = ((((kk << 2) + (l >> 4)) ^ (l & 7)) << 4);
      bf16x8 a[4], b[4];
#pragma unroll
      for (int m = 0; m < 4; m++)
        a[m] = *(const bf16x8*)(As_ + (arow + m * 16) * 128 + cx);
#pragma unroll
      for (int n = 0; n < 4; n++)
        b[n] = *(const bf16x8*)(Bs_ + (brw + n * 16) * 128 + cx);
#pragma unroll
      for (int m = 0; m < 4; m++)
#pragma unroll
        for (int n = 0; n < 4; n++)
          acc[m][n] = __builtin_amdgcn_mfma_f32_16x16x32_bf16(a[m], b[n], acc[m][n], 0, 0, 0);
    }
  };

  stage(A0, B0, 0);
  __syncthreads();
  for (int kt = 0; kt < nkt; kt += 2) {
    stage(A1, B1, kt + 1);
    compute(A0, B0);
    __syncthreads();
    if (kt + 2 < nkt) stage(A0, B0, kt + 2);
    compute(A1, B1);
    __syncthreads();
  }
}

// ---------------- 128x128 NT GEMM core, single-buffered (qk) ---------------
__device__ __forceinline__ void gemm_core_128_sb(
    const ushort* __restrict__ A, const ushort* __restrict__ B,
    int K, int brow, int bcol, f32x4 (&acc)[4][4], ushort* smem)
{
  ushort* As = smem;
  ushort* Bs = smem + 128 * 64;
  const int tid = threadIdx.x;
  const int w = tid >> 6, l = tid & 63;
  const int sr = (w << 3) + (l >> 3);
  const int sc = (((l & 7) ^ (l >> 3)) << 3);
  char* AsB = (char*)As;
  char* BsB = (char*)Bs;
  const int fr = l & 15;
  const int arow = ((w >> 1) << 6) + fr;
  const int brw  = ((w & 1) << 6) + fr;

#pragma unroll
  for (int m = 0; m < 4; m++)
#pragma unroll
    for (int n = 0; n < 4; n++)
      acc[m][n] = (f32x4){0.f, 0.f, 0.f, 0.f};

  const ushort* Ap = A + (long)(brow + sr) * K + sc;
  const ushort* Bp = B + (long)(bcol + sr) * K + sc;
  const int nkt = K >> 6;
  for (int kt = 0; kt < nkt; ++kt) {
#pragma unroll
    for (int i = 0; i < 4; i++) {
      gload16(Ap + (long)i * 32 * K, AsB + i * 4096 + (w << 10));
      gload16(Bp + (long)i * 32 * K, BsB + i * 4096 + (w << 10));
    }
    Ap += 64; Bp += 64;
    __syncthreads();
#pragma unroll
    for (int kk = 0; kk < 2; kk++) {
      const int cx = ((((kk << 2) + (l >> 4)) ^ (l & 7)) << 4);
      bf16x8 a[4], b[4];
#pragma unroll
      for (int m = 0; m < 4; m++)
        a[m] = *(const bf16x8*)(AsB + (arow + m * 16) * 128 + cx);
#pragma unroll
      for (int n = 0; n < 4; n++)
        b[n] = *(const bf16x8*)(BsB + (brw + n * 16) * 128 + cx);
#pragma unroll
      for (int m = 0; m < 4; m++)
#pragma unroll
        for (int n = 0; n < 4; n++)
          acc[m][n] = __builtin_amdgcn_mfma_f32_16x16x32_bf16(a[m], b[n], acc[m][n], 0, 0, 0);
    }
    __syncthreads();
  }
}

__device__ __forceinline__ void acc_to_lds_bf16(f32x4 (&acc)[4][4], ushort* smem) {
  const int tid = threadIdx.x, w = tid >> 6, l = tid & 63;
  const int r0l = ((w >> 1) << 6) + ((l >> 4) << 2);
  const int c0l = ((w & 1) << 6) + (l & 15);
#pragma unroll
  for (int n = 0; n < 4; n++)
#pragma unroll
    for (int m = 0; m < 4; m++)
#pragma unroll
      for (int j = 0; j < 4; j++)
        smem[(r0l + m * 16 + j) * 128 + (c0l + n * 16)] = f2b(acc[m][n][j]);
}

// ---------------- kernels ----------------

__global__ __launch_bounds__(256) void k_cvt(const float* __restrict__ in,
                                             ushort* __restrict__ out) {
  const long i = ((long)blockIdx.x * 256 + threadIdx.x) << 2;
  const float4 v = *(const float4*)(in + i);
  ushort4 o;
  o.x = f2b(v.x); o.y = f2b(v.y); o.z = f2b(v.z); o.w = f2b(v.w);
  *(ushort4*)(out + i) = o;
}

// pack mask (exactly 0.0/1.0) into 1 bit/element. 8192 waves, coalesced
// 256B-per-ballot reads at streaming BW; lane 0 stores the 64-bit ballot.
__global__ __launch_bounds__(256) void k_pack(const float* __restrict__ mask,
                                              unsigned long long* __restrict__ bits) {
  const int lane = threadIdx.x & 63;
  const long gwave = (long)blockIdx.x * 4 + (threadIdx.x >> 6);  // 8192 waves
  const long total = (long)NB * NN * NN;                         // 33.5M
  for (long base = gwave * 256; base < total; base += 8192L * 256) {
#pragma unroll
    for (int it = 0; it < 4; ++it) {
      const float v = mask[base + it * 64 + lane];
      const unsigned long long m = __ballot(v != 0.0f);
      if (lane == 0) bits[(base >> 6) + it] = m;
    }
  }
}

// out[C][R] = (bf16) in[R][C]  (fp32 weights only)
__global__ __launch_bounds__(256) void k_trw(const float* __restrict__ in, ushort* __restrict__ out,
                                             int R, int C) {
  __shared__ float t[32][33];
  const int c0 = blockIdx.x << 5, r0 = blockIdx.y << 5;
  const int tx = threadIdx.x & 31, ty = threadIdx.x >> 5;
#pragma unroll
  for (int j = 0; j < 32; j += 8)
    t[ty + j][tx] = in[(long)(r0 + ty + j) * C + (c0 + tx)];
  __syncthreads();
#pragma unroll
  for (int j = 0; j < 32; j += 8)
    out[(long)(c0 + ty + j) * R + (r0 + tx)] = f2b(t[tx][ty + j]);
}

__global__ __launch_bounds__(256) void k_gemm1(const ushort* __restrict__ xb,
                                               const ushort* __restrict__ w1t,
                                               const float* __restrict__ b1,
                                               ushort* __restrict__ hb) {
  __shared__ ushort smem[128 * 256];
  f32x4 acc[4][4];
  const int brow = blockIdx.x << 7, bcol = blockIdx.y << 7;
  gemm_core_128(xb, w1t, DM, brow, bcol, acc, smem);
  const int tid = threadIdx.x, w = tid >> 6, l = tid & 63;
  const int c0l = ((w & 1) << 6) + (l & 15);
#pragma unroll
  for (int n = 0; n < 4; n++) {
    const float bias = b1[bcol + c0l + n * 16];
#pragma unroll
    for (int m = 0; m < 4; m++)
#pragma unroll
      for (int j = 0; j < 4; j++) {
        float v = acc[m][n][j] + bias;
        acc[m][n][j] = v > 0.f ? v : 0.f;
      }
  }
  acc_to_lds_bf16(acc, smem);
  __syncthreads();
  const int rb = tid >> 4, cb = tid & 15;
#pragma unroll
  for (int i = 0; i < 8; i++) {
    const int row = i * 16 + rb;
    bf16x8 s = *(const bf16x8*)(smem + row * 128 + cb * 8);
    *(bf16x8*)(hb + (long)(brow + row) * DF + bcol + cb * 8) = s;
  }
}

// gemm2: k,q stored row-major; v stored TRANSPOSED directly into vtb[d][n]
__global__ __launch_bounds__(256) void k_gemm2(const ushort* __restrict__ hb,
                                               const ushort* __restrict__ w2t,
                                               const float* __restrict__ b2,
                                               ushort* __restrict__ kb,
                                               ushort* __restrict__ qb,
                                               ushort* __restrict__ vtb) {
  __shared__ ushort smem[128 * 256];
  f32x4 acc[4][4];
  const int brow = blockIdx.x << 7, bcol = blockIdx.y << 7;
  gemm_core_128(hb, w2t, DF, brow, bcol, acc, smem);
  const int seg = bcol >> 9;  // 0:k 1:q 2:v
  const float sc = (seg == 1) ? 0.04419417382415922f : 1.0f;  // 1/sqrt(512) into q
  const int tid = threadIdx.x, w = tid >> 6, l = tid & 63;
  const int c0l = ((w & 1) << 6) + (l & 15);
#pragma unroll
  for (int n = 0; n < 4; n++) {
    const float bias = b2[bcol + c0l + n * 16];
#pragma unroll
    for (int m = 0; m < 4; m++)
#pragma unroll
      for (int j = 0; j < 4; j++)
        acc[m][n][j] = (acc[m][n][j] + bias) * sc;
  }
  acc_to_lds_bf16(acc, smem);
  __syncthreads();
  const int clb = bcol - (seg << 9);
  if (seg < 2) {
    ushort* dst = (seg == 0) ? kb : qb;
    const int rb = tid >> 4, cb = tid & 15;
#pragma unroll
    for (int i = 0; i < 8; i++) {
      const int row = i * 16 + rb;
      bf16x8 s = *(const bf16x8*)(smem + row * 128 + cb * 8);
      *(bf16x8*)(dst + (long)(brow + row) * DM + clb + cb * 8) = s;
    }
  } else {
    // transposed store: vtb[batch][clb+c][token]
    const int batch = brow >> 11;
    const int rbase = brow & 2047;
    const int c = tid & 127, rc = tid >> 7;
    ushort* vt = vtb + (long)batch * DM * NN + (long)(clb + c) * NN + rbase;
#pragma unroll
    for (int it = 0; it < 8; ++it) {
      const int chunk = rc * 8 + it;  // 0..15
      bf16x8 o;
#pragma unroll
      for (int j = 0; j < 8; ++j)
        o[j] = (short)smem[(chunk * 8 + j) * 128 + c];
      *(bf16x8*)(vt + chunk * 8) = o;
    }
  }
}

// qk: r13 core/structure; mask applied from the 1-bit pack (L2-resident,
// 8x 1B loads/thread replacing 16x 16B HBM loads; select-by-bit is exact).
__global__ __launch_bounds__(256) void k_qk(const ushort* __restrict__ qb,
                                            const ushort* __restrict__ kb,
                                            const unsigned char* __restrict__ mbits,
                                            ushort* __restrict__ Sbuf) {
  __shared__ ushort smem[128 * 128];
  const int orig = blockIdx.x;          // 2048 blocks
  const int batch = orig & 7;           // XCD-pinned (round-robin dispatch)
  const int t = orig >> 3;              // 0..255
  const int bx = t & 15, by = t >> 4;
  const int brow = bx << 7, bcol = by << 7;
  const ushort* A = qb + (long)batch * NN * DM;
  const ushort* Bm = kb + (long)batch * NN * DM;
  const unsigned char* mb = mbits + (long)batch * (NN * NN / 8);
  ushort* S = Sbuf + (long)batch * NN * NN;
  f32x4 acc[4][4];
  gemm_core_128_sb(A, Bm, DM, brow, bcol, acc, smem);
  acc_to_lds_bf16(acc, smem);
  __syncthreads();
  const int tid = threadIdx.x, rb = tid >> 4, cb = tid & 15;
#pragma unroll
  for (int i = 0; i < 8; i++) {
    const int row = i * 16 + rb;
    const long goff = (long)(brow + row) * NN + bcol + cb * 8;
    bf16x8 s = *(const bf16x8*)(smem + row * 128 + cb * 8);
    const unsigned int bt = mb[goff >> 3];  // 8 bits for these 8 elements
    bf16x8 o;
#pragma unroll
    for (int j = 0; j < 8; ++j)
      o[j] = ((bt >> j) & 1) ? s[j] : (short)0;
    *(bf16x8*)(S + goff) = o;
  }
}

// pv: XCD-pinned flat grid -> per-batch vtb (2MB) becomes L2-resident.
__global__ __launch_bounds__(256) void k_pv(const ushort* __restrict__ Sbuf,
                                            const ushort* __restrict__ vtb,
                                            float* __restrict__ out) {
  __shared__ ushort smem[128 * 256];
  const int bid = blockIdx.x;          // 512 blocks
  const int batch = bid & 7;
  const int t = bid >> 3;              // 0..63
  const int brow = (t & 15) << 7;      // 16 row-tiles
  const int bcol = (t >> 4) << 7;      // 4 col-tiles
  const ushort* A = Sbuf + (long)batch * NN * NN;
  const ushort* Bm = vtb + (long)batch * DM * NN;  // v^T [512][2048]
  float* op = out + (long)batch * NN * DM;
  f32x4 acc[4][4];
  gemm_core_128(A, Bm, NN, brow, bcol, acc, smem);
  // LDS-roundtrip fp32 epilogue: coalesced float4 stores
  float* fs = (float*)smem;
  const int tid = threadIdx.x, w = tid >> 6, l = tid & 63;
  const int r0l = ((w >> 1) << 6) + ((l >> 4) << 2);
  const int c0l = ((w & 1) << 6) + (l & 15);
#pragma unroll
  for (int n = 0; n < 4; n++)
#pragma unroll
    for (int m = 0; m < 4; m++)
#pragma unroll
      for (int j = 0; j < 4; j++)
        fs[(r0l + m * 16 + j) * 128 + (c0l + n * 16)] = acc[m][n][j];
  __syncthreads();
  const int rg = tid >> 5, l32 = tid & 31;
#pragma unroll
  for (int p = 0; p < 16; ++p) {
    const int row = p * 8 + rg;
    const float4 v = *(const float4*)(fs + row * 128 + l32 * 4);
    *(float4*)(op + (long)(brow + row) * DM + bcol + l32 * 4) = v;
  }
}

// ---------------- launch ----------------
extern "C" void kernel_launch(void* const* d_in, const int* in_sizes, int n_in,
                              void* d_out, int out_size, void* d_ws, size_t ws_size,
                              hipStream_t stream) {
  const float* x    = (const float*)d_in[0];
  const float* mask = (const float*)d_in[1];
  const float* W1   = (const float*)d_in[2];
  const float* b1   = (const float*)d_in[3];
  const float* W2   = (const float*)d_in[4];
  const float* b2   = (const float*)d_in[5];
  float* out = (float*)d_out;

  char* ws = (char*)d_ws;
  size_t off = 0;
  auto alloc = [&](size_t n) { char* p = ws + off; off += (n + 255) & ~(size_t)255; return p; };
  ushort* xb  = (ushort*)alloc((size_t)NB * NN * DM * 2);
  ushort* hb  = (ushort*)alloc((size_t)NB * NN * DF * 2);
  ushort* w1t = (ushort*)alloc((size_t)DF * DM * 2);
  ushort* w2t = (ushort*)alloc((size_t)3 * DM * DF * 2);
  ushort* kb  = (ushort*)alloc((size_t)NB * NN * DM * 2);
  ushort* qb  = (ushort*)alloc((size_t)NB * NN * DM * 2);
  ushort* vtb = (ushort*)alloc((size_t)NB * NN * DM * 2);
  unsigned long long* mbits = (unsigned long long*)alloc((size_t)NB * NN * NN / 8);
  ushort* Sbuf = (ushort*)alloc((size_t)NB * NN * NN * 2);  // 67MB

  // mask -> 1 bit/element (exact: mask is 0.0/1.0)
  k_pack<<<dim3(2048), dim3(256), 0, stream>>>(mask, mbits);
  // x -> bf16
  k_cvt<<<dim3(8192), dim3(256), 0, stream>>>(x, xb);
  // W1 -> w1t ; W2 -> w2t
  k_trw<<<dim3(DF / 32, DM / 32), dim3(256), 0, stream>>>(W1, w1t, DM, DF);
  k_trw<<<dim3(3 * DM / 32, DF / 32), dim3(256), 0, stream>>>(W2, w2t, DF, 3 * DM);
  // h = relu(x@W1+b1)
  k_gemm1<<<dim3(NB * NN / 128, DF / 128), dim3(256), 0, stream>>>(xb, w1t, b1, hb);
  // kqv = h@W2+b2 (q pre-scaled; v written transposed into vtb)
  k_gemm2<<<dim3(NB * NN / 128, 3 * DM / 128), dim3(256), 0, stream>>>(hb, w2t, b2, kb, qb, vtb);
  // attention (split, S materialized in bf16; mask via bit-pack)
  k_qk<<<dim3(2048), dim3(256), 0, stream>>>(qb, kb, (const unsigned char*)mbits, Sbuf);
  k_pv<<<dim3(512), dim3(256), 0, stream>>>(Sbuf, vtb, out);
}

// Round 15
// 208.779 us; speedup vs baseline: 1.0990x; 1.0990x over previous
//
#include <hip/hip_runtime.h>
#include <hip/hip_bf16.h>

typedef __attribute__((ext_vector_type(8))) short bf16x8;
typedef __attribute__((ext_vector_type(4))) float f32x4;

#define NB 8
#define NN 2048
#define DM 512
#define DF 1024

__device__ __forceinline__ ushort f2b(float f) {
  union { __hip_bfloat16 h; ushort u; } c;
  c.h = __float2bfloat16(f);
  return c.u;
}
__device__ __forceinline__ float b2f(ushort u) {
  union { ushort u; __hip_bfloat16 h; } c;
  c.u = u;
  return __bfloat162float(c.h);
}

typedef __attribute__((address_space(1))) const void gvoid_t;
typedef __attribute__((address_space(3))) void svoid_t;
__device__ __forceinline__ void gload16(const void* g, void* s) {
  __builtin_amdgcn_global_load_lds((gvoid_t*)g, (svoid_t*)s, 16, 0, 0);
}

// ---------------- 128x128 NT GEMM core, double-buffered (gemm1/2, pv) ------
__device__ __forceinline__ void gemm_core_128(
    const ushort* __restrict__ A, const ushort* __restrict__ B,
    int K, int brow, int bcol, f32x4 (&acc)[4][4], ushort* smem)
{
  const int tid = threadIdx.x;
  const int w = tid >> 6, l = tid & 63;
  const int sr = (w << 3) + (l >> 3);
  const int sc = (((l & 7) ^ (l >> 3)) << 3);
  const int fr = l & 15;
  const int arow = ((w >> 1) << 6) + fr;
  const int brw  = ((w & 1) << 6) + fr;
  char* base = (char*)smem;
  char* A0 = base;          char* B0 = base + 16384;
  char* A1 = base + 32768;  char* B1 = base + 49152;

#pragma unroll
  for (int m = 0; m < 4; m++)
#pragma unroll
    for (int n = 0; n < 4; n++)
      acc[m][n] = (f32x4){0.f, 0.f, 0.f, 0.f};

  const ushort* Ap = A + (long)(brow + sr) * K + sc;
  const ushort* Bp = B + (long)(bcol + sr) * K + sc;
  const int nkt = K >> 6;

  auto stage = [&](char* Ad, char* Bd, int kt) {
#pragma unroll
    for (int i = 0; i < 4; i++) {
      gload16(Ap + (long)i * 32 * K + kt * 64, Ad + i * 4096 + (w << 10));
      gload16(Bp + (long)i * 32 * K + kt * 64, Bd + i * 4096 + (w << 10));
    }
  };
  auto compute = [&](const char* As_, const char* Bs_) {
#pragma unroll
    for (int kk = 0; kk < 2; kk++) {
      const int cx = ((((kk << 2) + (l >> 4)) ^ (l & 7)) << 4);
      bf16x8 a[4], b[4];
#pragma unroll
      for (int m = 0; m < 4; m++)
        a[m] = *(const bf16x8*)(As_ + (arow + m * 16) * 128 + cx);
#pragma unroll
      for (int n = 0; n < 4; n++)
        b[n] = *(const bf16x8*)(Bs_ + (brw + n * 16) * 128 + cx);
#pragma unroll
      for (int m = 0; m < 4; m++)
#pragma unroll
        for (int n = 0; n < 4; n++)
          acc[m][n] = __builtin_amdgcn_mfma_f32_16x16x32_bf16(a[m], b[n], acc[m][n], 0, 0, 0);
    }
  };

  stage(A0, B0, 0);
  __syncthreads();
  for (int kt = 0; kt < nkt; kt += 2) {
    stage(A1, B1, kt + 1);
    compute(A0, B0);
    __syncthreads();
    if (kt + 2 < nkt) stage(A0, B0, kt + 2);
    compute(A1, B1);
    __syncthreads();
  }
}

// ---------------- 128x128 NT GEMM core, single-buffered (qk) ---------------
__device__ __forceinline__ void gemm_core_128_sb(
    const ushort* __restrict__ A, const ushort* __restrict__ B,
    int K, int brow, int bcol, f32x4 (&acc)[4][4], ushort* smem)
{
  ushort* As = smem;
  ushort* Bs = smem + 128 * 64;
  const int tid = threadIdx.x;
  const int w = tid >> 6, l = tid & 63;
  const int sr = (w << 3) + (l >> 3);
  const int sc = (((l & 7) ^ (l >> 3)) << 3);
  char* AsB = (char*)As;
  char* BsB = (char*)Bs;
  const int fr = l & 15;
  const int arow = ((w >> 1) << 6) + fr;
  const int brw  = ((w & 1) << 6) + fr;

#pragma unroll
  for (int m = 0; m < 4; m++)
#pragma unroll
    for (int n = 0; n < 4; n++)
      acc[m][n] = (f32x4){0.f, 0.f, 0.f, 0.f};

  const ushort* Ap = A + (long)(brow + sr) * K + sc;
  const ushort* Bp = B + (long)(bcol + sr) * K + sc;
  const int nkt = K >> 6;
  for (int kt = 0; kt < nkt; ++kt) {
#pragma unroll
    for (int i = 0; i < 4; i++) {
      gload16(Ap + (long)i * 32 * K, AsB + i * 4096 + (w << 10));
      gload16(Bp + (long)i * 32 * K, BsB + i * 4096 + (w << 10));
    }
    Ap += 64; Bp += 64;
    __syncthreads();
#pragma unroll
    for (int kk = 0; kk < 2; kk++) {
      const int cx = ((((kk << 2) + (l >> 4)) ^ (l & 7)) << 4);
      bf16x8 a[4], b[4];
#pragma unroll
      for (int m = 0; m < 4; m++)
        a[m] = *(const bf16x8*)(AsB + (arow + m * 16) * 128 + cx);
#pragma unroll
      for (int n = 0; n < 4; n++)
        b[n] = *(const bf16x8*)(BsB + (brw + n * 16) * 128 + cx);
#pragma unroll
      for (int m = 0; m < 4; m++)
#pragma unroll
        for (int n = 0; n < 4; n++)
          acc[m][n] = __builtin_amdgcn_mfma_f32_16x16x32_bf16(a[m], b[n], acc[m][n], 0, 0, 0);
    }
    __syncthreads();
  }
}

__device__ __forceinline__ void acc_to_lds_bf16(f32x4 (&acc)[4][4], ushort* smem) {
  const int tid = threadIdx.x, w = tid >> 6, l = tid & 63;
  const int r0l = ((w >> 1) << 6) + ((l >> 4) << 2);
  const int c0l = ((w & 1) << 6) + (l & 15);
#pragma unroll
  for (int n = 0; n < 4; n++)
#pragma unroll
    for (int m = 0; m < 4; m++)
#pragma unroll
      for (int j = 0; j < 4; j++)
        smem[(r0l + m * 16 + j) * 128 + (c0l + n * 16)] = f2b(acc[m][n][j]);
}

// ---------------- kernels ----------------

__global__ __launch_bounds__(256) void k_cvt(const float* __restrict__ in,
                                             ushort* __restrict__ out) {
  const long i = ((long)blockIdx.x * 256 + threadIdx.x) << 2;
  const float4 v = *(const float4*)(in + i);
  ushort4 o;
  o.x = f2b(v.x); o.y = f2b(v.y); o.z = f2b(v.z); o.w = f2b(v.w);
  *(ushort4*)(out + i) = o;
}

// out[C][R] = (bf16) in[R][C]  (fp32 weights only)
__global__ __launch_bounds__(256) void k_trw(const float* __restrict__ in, ushort* __restrict__ out,
                                             int R, int C) {
  __shared__ float t[32][33];
  const int c0 = blockIdx.x << 5, r0 = blockIdx.y << 5;
  const int tx = threadIdx.x & 31, ty = threadIdx.x >> 5;
#pragma unroll
  for (int j = 0; j < 32; j += 8)
    t[ty + j][tx] = in[(long)(r0 + ty + j) * C + (c0 + tx)];
  __syncthreads();
#pragma unroll
  for (int j = 0; j < 32; j += 8)
    out[(long)(c0 + ty + j) * R + (r0 + tx)] = f2b(t[tx][ty + j]);
}

__global__ __launch_bounds__(256) void k_gemm1(const ushort* __restrict__ xb,
                                               const ushort* __restrict__ w1t,
                                               const float* __restrict__ b1,
                                               ushort* __restrict__ hb) {
  __shared__ ushort smem[128 * 256];
  f32x4 acc[4][4];
  const int brow = blockIdx.x << 7, bcol = blockIdx.y << 7;
  gemm_core_128(xb, w1t, DM, brow, bcol, acc, smem);
  const int tid = threadIdx.x, w = tid >> 6, l = tid & 63;
  const int c0l = ((w & 1) << 6) + (l & 15);
#pragma unroll
  for (int n = 0; n < 4; n++) {
    const float bias = b1[bcol + c0l + n * 16];
#pragma unroll
    for (int m = 0; m < 4; m++)
#pragma unroll
      for (int j = 0; j < 4; j++) {
        float v = acc[m][n][j] + bias;
        acc[m][n][j] = v > 0.f ? v : 0.f;
      }
  }
  acc_to_lds_bf16(acc, smem);
  __syncthreads();
  const int rb = tid >> 4, cb = tid & 15;
#pragma unroll
  for (int i = 0; i < 8; i++) {
    const int row = i * 16 + rb;
    bf16x8 s = *(const bf16x8*)(smem + row * 128 + cb * 8);
    *(bf16x8*)(hb + (long)(brow + row) * DF + bcol + cb * 8) = s;
  }
}

// gemm2: k,q stored row-major; v stored TRANSPOSED directly into vtb[d][n]
__global__ __launch_bounds__(256) void k_gemm2(const ushort* __restrict__ hb,
                                               const ushort* __restrict__ w2t,
                                               const float* __restrict__ b2,
                                               ushort* __restrict__ kb,
                                               ushort* __restrict__ qb,
                                               ushort* __restrict__ vtb) {
  __shared__ ushort smem[128 * 256];
  f32x4 acc[4][4];
  const int brow = blockIdx.x << 7, bcol = blockIdx.y << 7;
  gemm_core_128(hb, w2t, DF, brow, bcol, acc, smem);
  const int seg = bcol >> 9;  // 0:k 1:q 2:v
  const float sc = (seg == 1) ? 0.04419417382415922f : 1.0f;  // 1/sqrt(512) into q
  const int tid = threadIdx.x, w = tid >> 6, l = tid & 63;
  const int c0l = ((w & 1) << 6) + (l & 15);
#pragma unroll
  for (int n = 0; n < 4; n++) {
    const float bias = b2[bcol + c0l + n * 16];
#pragma unroll
    for (int m = 0; m < 4; m++)
#pragma unroll
      for (int j = 0; j < 4; j++)
        acc[m][n][j] = (acc[m][n][j] + bias) * sc;
  }
  acc_to_lds_bf16(acc, smem);
  __syncthreads();
  const int clb = bcol - (seg << 9);
  if (seg < 2) {
    ushort* dst = (seg == 0) ? kb : qb;
    const int rb = tid >> 4, cb = tid & 15;
#pragma unroll
    for (int i = 0; i < 8; i++) {
      const int row = i * 16 + rb;
      bf16x8 s = *(const bf16x8*)(smem + row * 128 + cb * 8);
      *(bf16x8*)(dst + (long)(brow + row) * DM + clb + cb * 8) = s;
    }
  } else {
    // transposed store: vtb[batch][clb+c][token]
    const int batch = brow >> 11;
    const int rbase = brow & 2047;
    const int c = tid & 127, rc = tid >> 7;
    ushort* vt = vtb + (long)batch * DM * NN + (long)(clb + c) * NN + rbase;
#pragma unroll
    for (int it = 0; it < 8; ++it) {
      const int chunk = rc * 8 + it;  // 0..15
      bf16x8 o;
#pragma unroll
      for (int j = 0; j < 8; ++j)
        o[j] = (short)smem[(chunk * 8 + j) * 128 + c];
      *(bf16x8*)(vt + chunk * 8) = o;
    }
  }
}

// qk: best measured form (r13, 78.5us): single-buffered core, XCD-pinned
// batch, NT fp32 mask loads in the LDS-roundtrip epilogue.
__global__ __launch_bounds__(256) void k_qk(const ushort* __restrict__ qb,
                                            const ushort* __restrict__ kb,
                                            const float* __restrict__ mask,
                                            ushort* __restrict__ Sbuf) {
  __shared__ ushort smem[128 * 128];
  const int orig = blockIdx.x;          // 2048 blocks
  const int batch = orig & 7;           // XCD-pinned (round-robin dispatch)
  const int t = orig >> 3;              // 0..255
  const int bx = t & 15, by = t >> 4;
  const int brow = bx << 7, bcol = by << 7;
  const ushort* A = qb + (long)batch * NN * DM;
  const ushort* Bm = kb + (long)batch * NN * DM;
  const float* mk = mask + (long)batch * NN * NN;
  ushort* S = Sbuf + (long)batch * NN * NN;
  f32x4 acc[4][4];
  gemm_core_128_sb(A, Bm, DM, brow, bcol, acc, smem);
  acc_to_lds_bf16(acc, smem);
  __syncthreads();
  const int tid = threadIdx.x, rb = tid >> 4, cb = tid & 15;
#pragma unroll
  for (int i = 0; i < 8; i++) {
    const int row = i * 16 + rb;
    const long goff = (long)(brow + row) * NN + bcol + cb * 8;
    bf16x8 s = *(const bf16x8*)(smem + row * 128 + cb * 8);
    const f32x4 m0 = __builtin_nontemporal_load((const f32x4*)(mk + goff));
    const f32x4 m1 = __builtin_nontemporal_load((const f32x4*)(mk + goff + 4));
    bf16x8 o;
    o[0] = (short)f2b(b2f((ushort)s[0]) * m0[0]);
    o[1] = (short)f2b(b2f((ushort)s[1]) * m0[1]);
    o[2] = (short)f2b(b2f((ushort)s[2]) * m0[2]);
    o[3] = (short)f2b(b2f((ushort)s[3]) * m0[3]);
    o[4] = (short)f2b(b2f((ushort)s[4]) * m1[0]);
    o[5] = (short)f2b(b2f((ushort)s[5]) * m1[1]);
    o[6] = (short)f2b(b2f((ushort)s[6]) * m1[2]);
    o[7] = (short)f2b(b2f((ushort)s[7]) * m1[3]);
    *(bf16x8*)(S + goff) = o;
  }
}

// pv: XCD-pinned flat grid -> per-batch vtb (2MB) becomes L2-resident.
__global__ __launch_bounds__(256) void k_pv(const ushort* __restrict__ Sbuf,
                                            const ushort* __restrict__ vtb,
                                            float* __restrict__ out) {
  __shared__ ushort smem[128 * 256];
  const int bid = blockIdx.x;          // 512 blocks
  const int batch = bid & 7;
  const int t = bid >> 3;              // 0..63
  const int brow = (t & 15) << 7;      // 16 row-tiles
  const int bcol = (t >> 4) << 7;      // 4 col-tiles
  const ushort* A = Sbuf + (long)batch * NN * NN;
  const ushort* Bm = vtb + (long)batch * DM * NN;  // v^T [512][2048]
  float* op = out + (long)batch * NN * DM;
  f32x4 acc[4][4];
  gemm_core_128(A, Bm, NN, brow, bcol, acc, smem);
  // LDS-roundtrip fp32 epilogue: coalesced float4 stores
  float* fs = (float*)smem;
  const int tid = threadIdx.x, w = tid >> 6, l = tid & 63;
  const int r0l = ((w >> 1) << 6) + ((l >> 4) << 2);
  const int c0l = ((w & 1) << 6) + (l & 15);
#pragma unroll
  for (int n = 0; n < 4; n++)
#pragma unroll
    for (int m = 0; m < 4; m++)
#pragma unroll
      for (int j = 0; j < 4; j++)
        fs[(r0l + m * 16 + j) * 128 + (c0l + n * 16)] = acc[m][n][j];
  __syncthreads();
  const int rg = tid >> 5, l32 = tid & 31;
#pragma unroll
  for (int p = 0; p < 16; ++p) {
    const int row = p * 8 + rg;
    const float4 v = *(const float4*)(fs + row * 128 + l32 * 4);
    *(float4*)(op + (long)(brow + row) * DM + bcol + l32 * 4) = v;
  }
}

// ---------------- launch ----------------
extern "C" void kernel_launch(void* const* d_in, const int* in_sizes, int n_in,
                              void* d_out, int out_size, void* d_ws, size_t ws_size,
                              hipStream_t stream) {
  const float* x    = (const float*)d_in[0];
  const float* mask = (const float*)d_in[1];
  const float* W1   = (const float*)d_in[2];
  const float* b1   = (const float*)d_in[3];
  const float* W2   = (const float*)d_in[4];
  const float* b2   = (const float*)d_in[5];
  float* out = (float*)d_out;

  char* ws = (char*)d_ws;
  size_t off = 0;
  auto alloc = [&](size_t n) { char* p = ws + off; off += (n + 255) & ~(size_t)255; return p; };
  ushort* xb  = (ushort*)alloc((size_t)NB * NN * DM * 2);
  ushort* hb  = (ushort*)alloc((size_t)NB * NN * DF * 2);
  ushort* w1t = (ushort*)alloc((size_t)DF * DM * 2);
  ushort* w2t = (ushort*)alloc((size_t)3 * DM * DF * 2);
  ushort* kb  = (ushort*)alloc((size_t)NB * NN * DM * 2);
  ushort* qb  = (ushort*)alloc((size_t)NB * NN * DM * 2);
  ushort* vtb = (ushort*)alloc((size_t)NB * NN * DM * 2);
  ushort* Sbuf = (ushort*)alloc((size_t)NB * NN * NN * 2);  // 67MB

  // x -> bf16
  k_cvt<<<dim3(8192), dim3(256), 0, stream>>>(x, xb);
  // W1 -> w1t ; W2 -> w2t
  k_trw<<<dim3(DF / 32, DM / 32), dim3(256), 0, stream>>>(W1, w1t, DM, DF);
  k_trw<<<dim3(3 * DM / 32, DF / 32), dim3(256), 0, stream>>>(W2, w2t, DF, 3 * DM);
  // h = relu(x@W1+b1)
  k_gemm1<<<dim3(NB * NN / 128, DF / 128), dim3(256), 0, stream>>>(xb, w1t, b1, hb);
  // kqv = h@W2+b2 (q pre-scaled; v written transposed into vtb)
  k_gemm2<<<dim3(NB * NN / 128, 3 * DM / 128), dim3(256), 0, stream>>>(hb, w2t, b2, kb, qb, vtb);
  // attention (split, S materialized in bf16)
  k_qk<<<dim3(2048), dim3(256), 0, stream>>>(qb, kb, mask, Sbuf);
  k_pv<<<dim3(512), dim3(256), 0, stream>>>(Sbuf, vtb, out);
}